// Round 5
// baseline (138.731 us; speedup 1.0000x reference)
//
#include <hip/hip_runtime.h>

#define TPB 256

// lgkm-only barrier: orders LDS ops across the block without draining the
// global-store queue (HIP's __syncthreads emits s_waitcnt vmcnt(0)).
__device__ __forceinline__ void block_sync_lds() {
    asm volatile("s_waitcnt lgkmcnt(0)" ::: "memory");
    __builtin_amdgcn_s_barrier();
    asm volatile("" ::: "memory");
}

// Force a wave-uniform float into an SGPR.
__device__ __forceinline__ float sgpr(float x) {
    return __int_as_float(__builtin_amdgcn_readfirstlane(__float_as_int(x)));
}

// ---------------------------------------------------------------------------
// 3x3 QR (LAPACK Householder convention). M = Phi_P[level] row-major;
// P out = Phi[level] row-major (orthonormal rows).
// ---------------------------------------------------------------------------
__device__ __forceinline__ void qr3(const float* __restrict__ M, float* __restrict__ P) {
    float A[3][3];
#pragma unroll
    for (int r = 0; r < 3; ++r)
#pragma unroll
        for (int c = 0; c < 3; ++c)
            A[r][c] = M[c * 3 + r];  // A = Phi_P^T

    float V[3][3], tau[3];
#pragma unroll
    for (int k = 0; k < 3; ++k) {
        float alpha = A[k][k];
        float xn2 = 0.f;
#pragma unroll
        for (int r = k + 1; r < 3; ++r) xn2 += A[r][k] * A[r][k];
        float t = 0.f;
        float v[3] = {0.f, 0.f, 0.f};
        v[k] = 1.f;
        if (xn2 > 0.f) {
            float beta = -copysignf(sqrtf(alpha * alpha + xn2), alpha);
            t = (beta - alpha) / beta;
            float inv = 1.f / (alpha - beta);
#pragma unroll
            for (int r = k + 1; r < 3; ++r) v[r] = A[r][k] * inv;
#pragma unroll
            for (int c = 0; c < 3; ++c) {
                if (c < k) continue;
                float w = 0.f;
#pragma unroll
                for (int r = 0; r < 3; ++r) if (r >= k) w += v[r] * A[r][c];
                w *= t;
#pragma unroll
                for (int r = 0; r < 3; ++r) if (r >= k) A[r][c] -= w * v[r];
            }
        }
        tau[k] = t;
#pragma unroll
        for (int r = 0; r < 3; ++r) V[k][r] = v[r];
    }
    float Q[3][3] = {{1.f, 0.f, 0.f}, {0.f, 1.f, 0.f}, {0.f, 0.f, 1.f}};
#pragma unroll
    for (int k = 2; k >= 0; --k) {
#pragma unroll
        for (int c = 0; c < 3; ++c) {
            float w = 0.f;
#pragma unroll
            for (int r = 0; r < 3; ++r) w += V[k][r] * Q[r][c];
            w *= tau[k];
#pragma unroll
            for (int r = 0; r < 3; ++r) Q[r][c] -= w * V[k][r];
        }
    }
#pragma unroll
    for (int r = 0; r < 3; ++r)
#pragma unroll
        for (int c = 0; c < 3; ++c)
            P[r * 3 + c] = Q[c][r];  // Phi = Q^T
}

// ---------------------------------------------------------------------------
// Fused 3 levels, R1-style I/O + lgkm-only sync. Block handles 256 L2-triples
// = 2304 L0 triples = 6912 input floats. Thread t owns input floats
// [27t, 27t+27) of the block chunk -> its 9 L0 triples, 3 L1 triples, 1 L2
// triple are all thread-local (no shuffles). One 27KB LDS buffer is used for
// the input transpose, then reused to stage all detail outputs so every
// global load/store round is dense and coalesced. 4 lgkm-only barriers; the
// global store queue is never drained inside the kernel.
// ---------------------------------------------------------------------------
__global__ __launch_bounds__(TPB) void fused3_kernel(
        const float* __restrict__ in, float* __restrict__ out,
        float* __restrict__ avg_out, const float* __restrict__ PhiP,
        int lvl, int m2) {
    __shared__ float s[6912];
    const int  t = threadIdx.x;
    const long b = blockIdx.x;
    const long nF = 27L * m2;                 // total input floats
    const long fBase = 6912L * b;             // block's first input float
    const long M0 = 9L * m2, M1 = 3L * m2, M2 = m2;

    const bool fullLoad = (fBase + 6912 <= nF);

    // ---- Phase A: coalesced float4 loads (issued before QR to hide latency)
    float4 v[7];
    if (fullLoad) {
        const float4* p4 = reinterpret_cast<const float4*>(in + fBase);
#pragma unroll
        for (int r = 0; r < 6; ++r) v[r] = p4[256 * r + t];
        if (t < 192) v[6] = p4[1536 + t];
    }

    // ---- QR for the 3 levels (overlaps global-load latency)
    float P[27];
    qr3(PhiP + 9L * lvl,       P + 0);
    qr3(PhiP + 9L * (lvl + 1), P + 9);
    qr3(PhiP + 9L * (lvl + 2), P + 18);
#pragma unroll
    for (int j = 0; j < 27; ++j) P[j] = sgpr(P[j]);

    // ---- LDS fill
    if (fullLoad) {
#pragma unroll
        for (int r = 0; r < 6; ++r)
            *reinterpret_cast<float4*>(&s[4 * (256 * r + t)]) = v[r];
        if (t < 192)
            *reinterpret_cast<float4*>(&s[4 * (1536 + t)]) = v[6];
    } else {
        const long rem = nF - fBase;
        for (int i = t; i < 6912; i += TPB) s[i] = (i < rem) ? in[fBase + i] : 0.f;
    }
    block_sync_lds();

    // ---- Phase B: transpose read, 27 consecutive floats per thread
    float f[27];
#pragma unroll
    for (int j = 0; j < 27; ++j) f[j] = s[27 * t + j];
    block_sync_lds();  // all reads done before s is overwritten

    // ---- Phase C: compute all 3 levels in registers, stage details in s
    // layout: [0,2304) d1L0 | [2304,4608) d2L0 | [4608,5376) d1L1 |
    //         [5376,6144) d2L1 | [6144,6400) d1L2 | [6400,6656) d2L2
    float a[9];
#pragma unroll
    for (int g = 0; g < 9; ++g) {
        float x = f[3 * g], y = f[3 * g + 1], z = f[3 * g + 2];
        a[g] = x * P[0] + y * P[1] + z * P[2];
        s[9 * t + g]        = x * P[3] + y * P[4] + z * P[5];
        s[2304 + 9 * t + g] = x * P[6] + y * P[7] + z * P[8];
    }
    float bb[3];
#pragma unroll
    for (int h = 0; h < 3; ++h) {
        float x = a[3 * h], y = a[3 * h + 1], z = a[3 * h + 2];
        bb[h] = x * P[9] + y * P[10] + z * P[11];
        s[4608 + 3 * t + h] = x * P[12] + y * P[13] + z * P[14];
        s[5376 + 3 * t + h] = x * P[15] + y * P[16] + z * P[17];
    }
    float c;
    {
        float x = bb[0], y = bb[1], z = bb[2];
        c = x * P[18] + y * P[19] + z * P[20];
        s[6144 + t] = x * P[21] + y * P[22] + z * P[23];
        s[6400 + t] = x * P[24] + y * P[25] + z * P[26];
    }
    block_sync_lds();

    // ---- Phase D: dense coalesced store rounds (queue, never wait)
    const bool fullStore = (2304L * (b + 1) <= M0);
    if (fullStore) {
        const long g0 = 2304 * b, g1 = 768 * b, g2 = 256 * b;
#pragma unroll
        for (int r = 0; r < 9; ++r) out[M0 + g0 + 256 * r + t]     = s[256 * r + t];
#pragma unroll
        for (int r = 0; r < 9; ++r) out[2 * M0 + g0 + 256 * r + t] = s[2304 + 256 * r + t];
#pragma unroll
        for (int r = 0; r < 3; ++r) out[M1 + g1 + 256 * r + t]     = s[4608 + 256 * r + t];
#pragma unroll
        for (int r = 0; r < 3; ++r) out[2 * M1 + g1 + 256 * r + t] = s[5376 + 256 * r + t];
        out[M2 + g2 + t]     = s[6144 + t];
        out[2 * M2 + g2 + t] = s[6400 + t];
        avg_out[g2 + t]      = c;
    } else {
#pragma unroll
        for (int r = 0; r < 9; ++r) {
            long i = 256 * r + t, g = 2304 * b + i;
            if (g < M0) { out[M0 + g] = s[i]; out[2 * M0 + g] = s[2304 + i]; }
        }
#pragma unroll
        for (int r = 0; r < 3; ++r) {
            long i = 256 * r + t, g = 768 * b + i;
            if (g < M1) { out[M1 + g] = s[4608 + i]; out[2 * M1 + g] = s[5376 + i]; }
        }
        long g = 256 * b + t;
        if (g < M2) {
            out[M2 + g]     = s[6144 + t];
            out[2 * M2 + g] = s[6400 + t];
            avg_out[g]      = c;
        }
    }
}

// ---------------------------------------------------------------------------
// Tail: levels 9..15, one block of 1024 threads, LDS ping-pong.
// QR for the 7 levels computed by 7 parallel lanes of wave 0.
// ---------------------------------------------------------------------------
#define TTPB 1024
__global__ __launch_bounds__(TTPB) void tail_kernel(
        const float* __restrict__ in, float* __restrict__ out,
        const float* __restrict__ PhiP) {
    __shared__ float s0[2187];
    __shared__ float s1[729];
    __shared__ float sPhi[63];
    const int lt = threadIdx.x;

    for (int i = lt; i < 2187; i += TTPB) s0[i] = in[i];
    if (lt < 7) {
        float P[9];
        qr3(PhiP + 9L * (9 + lt), P);
#pragma unroll
        for (int j = 0; j < 9; ++j) sPhi[lt * 9 + j] = P[j];
    }
    __syncthreads();

    float* cur = s0;
    float* nxt = s1;
    int len = 2187;
#pragma unroll
    for (int L = 0; L < 7; ++L) {
        int m = len / 3;
        float p0 = sPhi[L * 9 + 0], p1 = sPhi[L * 9 + 1], p2 = sPhi[L * 9 + 2];
        float q0 = sPhi[L * 9 + 3], q1 = sPhi[L * 9 + 4], q2 = sPhi[L * 9 + 5];
        float r0 = sPhi[L * 9 + 6], r1 = sPhi[L * 9 + 7], r2 = sPhi[L * 9 + 8];
        for (int t = lt; t < m; t += TTPB) {
            float x = cur[3 * t], y = cur[3 * t + 1], z = cur[3 * t + 2];
            out[m + t]     = x * q0 + y * q1 + z * q2;
            out[2 * m + t] = x * r0 + y * r1 + z * r2;
            nxt[t]         = x * p0 + y * p1 + z * p2;
        }
        block_sync_lds();
        float* tmp = cur; cur = nxt; nxt = tmp;
        len = m;
    }
    if (lt == 0) out[0] = cur[0];
}

extern "C" void kernel_launch(void* const* d_in, const int* in_sizes, int n_in,
                              void* d_out, int out_size, void* d_ws, size_t ws_size,
                              hipStream_t stream) {
    const float* f    = (const float*)d_in[0];   // 3^16 floats
    const float* PhiP = (const float*)d_in[1];   // 16*3*3 floats
    float* out = (float*)d_out;                  // 3^16 floats
    float* ws  = (float*)d_ws;

    float* bufA = ws;                // 3^13 floats
    float* bufB = bufA + 1594323;    // 3^10 floats
    float* bufC = bufB + 59049;      // 3^7  floats

    const int m2_0 = 1594323;  // 3^13, levels 0-2
    fused3_kernel<<<(m2_0 + TPB - 1) / TPB, TPB, 0, stream>>>(f, out, bufA, PhiP, 0, m2_0);

    const int m2_1 = 59049;    // 3^10, levels 3-5
    fused3_kernel<<<(m2_1 + TPB - 1) / TPB, TPB, 0, stream>>>(bufA, out, bufB, PhiP, 3, m2_1);

    const int m2_2 = 2187;     // 3^7, levels 6-8
    fused3_kernel<<<(m2_2 + TPB - 1) / TPB, TPB, 0, stream>>>(bufB, out, bufC, PhiP, 6, m2_2);

    tail_kernel<<<1, TTPB, 0, stream>>>(bufC, out, PhiP);
}

// Round 7
// 85.021 us; speedup vs baseline: 1.6317x; 1.6317x over previous
//
#include <hip/hip_runtime.h>

#define TPB 256

typedef float f32x4 __attribute__((ext_vector_type(4)));

// lgkm-only barrier: orders LDS ops across the block without draining the
// global-store queue (HIP's __syncthreads emits s_waitcnt vmcnt(0)).
__device__ __forceinline__ void block_sync_lds() {
    asm volatile("s_waitcnt lgkmcnt(0)" ::: "memory");
    __builtin_amdgcn_s_barrier();
    asm volatile("" ::: "memory");
}

// Force a wave-uniform float into an SGPR.
__device__ __forceinline__ float sgpr(float x) {
    return __int_as_float(__builtin_amdgcn_readfirstlane(__float_as_int(x)));
}

// ---------------------------------------------------------------------------
// 3x3 QR (LAPACK Householder convention). M = Phi_P[level] row-major;
// P out = Phi[level] row-major (orthonormal rows).
// ---------------------------------------------------------------------------
__device__ __forceinline__ void qr3(const float* __restrict__ M, float* __restrict__ P) {
    float A[3][3];
#pragma unroll
    for (int r = 0; r < 3; ++r)
#pragma unroll
        for (int c = 0; c < 3; ++c)
            A[r][c] = M[c * 3 + r];  // A = Phi_P^T

    float V[3][3], tau[3];
#pragma unroll
    for (int k = 0; k < 3; ++k) {
        float alpha = A[k][k];
        float xn2 = 0.f;
#pragma unroll
        for (int r = k + 1; r < 3; ++r) xn2 += A[r][k] * A[r][k];
        float t = 0.f;
        float v[3] = {0.f, 0.f, 0.f};
        v[k] = 1.f;
        if (xn2 > 0.f) {
            float beta = -copysignf(sqrtf(alpha * alpha + xn2), alpha);
            t = (beta - alpha) / beta;
            float inv = 1.f / (alpha - beta);
#pragma unroll
            for (int r = k + 1; r < 3; ++r) v[r] = A[r][k] * inv;
#pragma unroll
            for (int c = 0; c < 3; ++c) {
                if (c < k) continue;
                float w = 0.f;
#pragma unroll
                for (int r = 0; r < 3; ++r) if (r >= k) w += v[r] * A[r][c];
                w *= t;
#pragma unroll
                for (int r = 0; r < 3; ++r) if (r >= k) A[r][c] -= w * v[r];
            }
        }
        tau[k] = t;
#pragma unroll
        for (int r = 0; r < 3; ++r) V[k][r] = v[r];
    }
    float Q[3][3] = {{1.f, 0.f, 0.f}, {0.f, 1.f, 0.f}, {0.f, 0.f, 1.f}};
#pragma unroll
    for (int k = 2; k >= 0; --k) {
#pragma unroll
        for (int c = 0; c < 3; ++c) {
            float w = 0.f;
#pragma unroll
            for (int r = 0; r < 3; ++r) w += V[k][r] * Q[r][c];
            w *= tau[k];
#pragma unroll
            for (int r = 0; r < 3; ++r) Q[r][c] -= w * V[k][r];
        }
    }
#pragma unroll
    for (int r = 0; r < 3; ++r)
#pragma unroll
        for (int c = 0; c < 3; ++c)
            P[r * 3 + c] = Q[c][r];  // Phi = Q^T
}

// LDS staging origins (each section padded +8 for the alignment shift)
#define ORG_D1L0 0
#define ORG_D2L0 2312
#define ORG_D1L1 4624
#define ORG_D2L1 5400
#define ORG_D1L2 6176
#define ORG_D2L2 6440

// ---------------------------------------------------------------------------
// Fused 3 levels. Block = 256 L2-triples = 2304 L0 triples = 6912 input
// floats. Thread t owns input floats [27t,27t+27) -> all its triples are
// thread-local (no shuffles). Input: coalesced float4 loads -> LDS ->
// 27-consecutive read. Details staged in LDS (shifted by A&3 so Phase-D LDS
// reads are 16B-aligned), then stored as NONTEMPORAL f32x4 (head/tail dwords
// handle the odd section offsets). lgkm-only barriers; store queue never
// drained in-kernel. nt keeps `out` from evicting f's L3 residency (R5
// lesson: plain stores doubled both FETCH and WRITE).
// ---------------------------------------------------------------------------
__global__ __launch_bounds__(TPB) void fused3_kernel(
        const float* __restrict__ in, float* __restrict__ out,
        float* __restrict__ avg_out, const float* __restrict__ PhiP,
        int lvl, int m2) {
    __shared__ float s[6912];
    const int  t = threadIdx.x;
    const long b = blockIdx.x;
    const long nF = 27L * m2;
    const long fBase = 6912L * b;
    const long M0 = 9L * m2, M1 = 3L * m2, M2 = m2;

    const bool full = (256L * (b + 1) <= (long)m2);  // all 256 L2-triples valid

    // global element offsets of this block's 6 detail chunks
    const long A0 = M0 + 2304L * b;
    const long A1 = 2 * M0 + 2304L * b;
    const long A2 = M1 + 768L * b;
    const long A3 = 2 * M1 + 768L * b;
    const long A4 = M2 + 256L * b;
    const long A5 = 2 * M2 + 256L * b;
    const int o0 = (int)(A0 & 3), o1 = (int)(A1 & 3), o2 = (int)(A2 & 3);
    const int o3 = (int)(A3 & 3), o4 = (int)(A4 & 3), o5 = (int)(A5 & 3);

    // ---- Phase A: coalesced float4 loads (issued before QR to hide latency)
    f32x4 v[7];
    if (full) {
        const f32x4* p4 = reinterpret_cast<const f32x4*>(in + fBase);
#pragma unroll
        for (int r = 0; r < 6; ++r) v[r] = p4[256 * r + t];
        if (t < 192) v[6] = p4[1536 + t];
    }

    // ---- QR for the 3 levels (overlaps global-load latency)
    float P[27];
    qr3(PhiP + 9L * lvl,       P + 0);
    qr3(PhiP + 9L * (lvl + 1), P + 9);
    qr3(PhiP + 9L * (lvl + 2), P + 18);
#pragma unroll
    for (int j = 0; j < 27; ++j) P[j] = sgpr(P[j]);

    // ---- LDS fill
    if (full) {
#pragma unroll
        for (int r = 0; r < 6; ++r)
            *reinterpret_cast<f32x4*>(&s[4 * (256 * r + t)]) = v[r];
        if (t < 192)
            *reinterpret_cast<f32x4*>(&s[4 * (1536 + t)]) = v[6];
    } else {
        const long rem = nF - fBase;
        for (int i = t; i < 6912; i += TPB) s[i] = (i < rem) ? in[fBase + i] : 0.f;
    }
    block_sync_lds();

    // ---- Phase B: transpose read, 27 consecutive floats per thread
    float f[27];
#pragma unroll
    for (int j = 0; j < 27; ++j) f[j] = s[27 * t + j];
    block_sync_lds();  // all reads done before s is overwritten

    // ---- Phase C: compute 3 levels in registers, stage details (shifted)
    float a[9];
#pragma unroll
    for (int g = 0; g < 9; ++g) {
        float x = f[3 * g], y = f[3 * g + 1], z = f[3 * g + 2];
        a[g] = x * P[0] + y * P[1] + z * P[2];
        s[ORG_D1L0 + o0 + 9 * t + g] = x * P[3] + y * P[4] + z * P[5];
        s[ORG_D2L0 + o1 + 9 * t + g] = x * P[6] + y * P[7] + z * P[8];
    }
    float bb[3];
#pragma unroll
    for (int h = 0; h < 3; ++h) {
        float x = a[3 * h], y = a[3 * h + 1], z = a[3 * h + 2];
        bb[h] = x * P[9] + y * P[10] + z * P[11];
        s[ORG_D1L1 + o2 + 3 * t + h] = x * P[12] + y * P[13] + z * P[14];
        s[ORG_D2L1 + o3 + 3 * t + h] = x * P[15] + y * P[16] + z * P[17];
    }
    float c;
    {
        float x = bb[0], y = bb[1], z = bb[2];
        c = x * P[18] + y * P[19] + z * P[20];
        s[ORG_D1L2 + o4 + t] = x * P[21] + y * P[22] + z * P[23];
        s[ORG_D2L2 + o5 + t] = x * P[24] + y * P[25] + z * P[26];
    }
    block_sync_lds();

    // ---- Phase D: nontemporal f32x4 store rounds (queue, never wait)
#define STORE_SEC(ORG, A, O, CNT, ROUNDS)                                      \
    {                                                                          \
        float* dst = out + (A);                                                \
        const int aH = (4 - (O)) & 3;                                          \
        const int nb = ((CNT) - aH) >> 2;                                      \
        const int tl = (CNT) - aH - 4 * nb;                                    \
        if (t < aH) __builtin_nontemporal_store(s[(ORG) + (O) + t], dst + t);  \
        _Pragma("unroll")                                                      \
        for (int r = 0; r < (ROUNDS); ++r) {                                   \
            int idx = 256 * r + t;                                             \
            if (idx < nb) {                                                    \
                f32x4 vv = *reinterpret_cast<const f32x4*>(                    \
                    &s[(ORG) + (O) + aH + 4 * idx]);                           \
                __builtin_nontemporal_store(                                   \
                    vv, reinterpret_cast<f32x4*>(dst + aH) + idx);             \
            }                                                                  \
        }                                                                      \
        if (t < tl)                                                            \
            __builtin_nontemporal_store(s[(ORG) + (O) + aH + 4 * nb + t],      \
                                        dst + aH + 4 * nb + t);                \
    }

    if (full) {
        STORE_SEC(ORG_D1L0, A0, o0, 2304, 3);
        STORE_SEC(ORG_D2L0, A1, o1, 2304, 3);
        STORE_SEC(ORG_D1L1, A2, o2, 768, 1);
        STORE_SEC(ORG_D2L1, A3, o3, 768, 1);
        STORE_SEC(ORG_D1L2, A4, o4, 256, 1);
        STORE_SEC(ORG_D2L2, A5, o5, 256, 1);
        avg_out[256L * b + t] = c;
    } else {
        // boundary block: bounds-checked dword stores from the shifted staging
#pragma unroll
        for (int r = 0; r < 9; ++r) {
            long i = 256 * r + t, g = 2304L * b + i;
            if (g < M0) {
                __builtin_nontemporal_store(s[ORG_D1L0 + o0 + i], out + M0 + g);
                __builtin_nontemporal_store(s[ORG_D2L0 + o1 + i], out + 2 * M0 + g);
            }
        }
#pragma unroll
        for (int r = 0; r < 3; ++r) {
            long i = 256 * r + t, g = 768L * b + i;
            if (g < M1) {
                __builtin_nontemporal_store(s[ORG_D1L1 + o2 + i], out + M1 + g);
                __builtin_nontemporal_store(s[ORG_D2L1 + o3 + i], out + 2 * M1 + g);
            }
        }
        long g = 256L * b + t;
        if (g < M2) {
            __builtin_nontemporal_store(s[ORG_D1L2 + o4 + t], out + M2 + g);
            __builtin_nontemporal_store(s[ORG_D2L2 + o5 + t], out + 2 * M2 + g);
            avg_out[g] = c;
        }
    }
#undef STORE_SEC
}

// ---------------------------------------------------------------------------
// Tail: levels 9..15, one block of 1024 threads, LDS ping-pong.
// QR for the 7 levels computed by 7 parallel lanes of wave 0.
// ---------------------------------------------------------------------------
#define TTPB 1024
__global__ __launch_bounds__(TTPB) void tail_kernel(
        const float* __restrict__ in, float* __restrict__ out,
        const float* __restrict__ PhiP) {
    __shared__ float s0[2187];
    __shared__ float s1[729];
    __shared__ float sPhi[63];
    const int lt = threadIdx.x;

    for (int i = lt; i < 2187; i += TTPB) s0[i] = in[i];
    if (lt < 7) {
        float P[9];
        qr3(PhiP + 9L * (9 + lt), P);
#pragma unroll
        for (int j = 0; j < 9; ++j) sPhi[lt * 9 + j] = P[j];
    }
    __syncthreads();

    float* cur = s0;
    float* nxt = s1;
    int len = 2187;
#pragma unroll
    for (int L = 0; L < 7; ++L) {
        int m = len / 3;
        float p0 = sPhi[L * 9 + 0], p1 = sPhi[L * 9 + 1], p2 = sPhi[L * 9 + 2];
        float q0 = sPhi[L * 9 + 3], q1 = sPhi[L * 9 + 4], q2 = sPhi[L * 9 + 5];
        float r0 = sPhi[L * 9 + 6], r1 = sPhi[L * 9 + 7], r2 = sPhi[L * 9 + 8];
        for (int t = lt; t < m; t += TTPB) {
            float x = cur[3 * t], y = cur[3 * t + 1], z = cur[3 * t + 2];
            out[m + t]     = x * q0 + y * q1 + z * q2;
            out[2 * m + t] = x * r0 + y * r1 + z * r2;
            nxt[t]         = x * p0 + y * p1 + z * p2;
        }
        block_sync_lds();
        float* tmp = cur; cur = nxt; nxt = tmp;
        len = m;
    }
    if (lt == 0) out[0] = cur[0];
}

extern "C" void kernel_launch(void* const* d_in, const int* in_sizes, int n_in,
                              void* d_out, int out_size, void* d_ws, size_t ws_size,
                              hipStream_t stream) {
    const float* f    = (const float*)d_in[0];   // 3^16 floats
    const float* PhiP = (const float*)d_in[1];   // 16*3*3 floats
    float* out = (float*)d_out;                  // 3^16 floats
    float* ws  = (float*)d_ws;

    float* bufA = ws;                // 3^13 floats
    float* bufB = bufA + 1594323;    // 3^10 floats
    float* bufC = bufB + 59049;      // 3^7  floats

    const int m2_0 = 1594323;  // 3^13, levels 0-2
    fused3_kernel<<<(m2_0 + TPB - 1) / TPB, TPB, 0, stream>>>(f, out, bufA, PhiP, 0, m2_0);

    const int m2_1 = 59049;    // 3^10, levels 3-5
    fused3_kernel<<<(m2_1 + TPB - 1) / TPB, TPB, 0, stream>>>(bufA, out, bufB, PhiP, 3, m2_1);

    const int m2_2 = 2187;     // 3^7, levels 6-8
    fused3_kernel<<<(m2_2 + TPB - 1) / TPB, TPB, 0, stream>>>(bufB, out, bufC, PhiP, 6, m2_2);

    tail_kernel<<<1, TTPB, 0, stream>>>(bufC, out, PhiP);
}

// Round 8
// 83.807 us; speedup vs baseline: 1.6554x; 1.0145x over previous
//
#include <hip/hip_runtime.h>

#define TPB 256

typedef float f32x4 __attribute__((ext_vector_type(4)));

// lgkm-only barrier: orders LDS ops across the block without draining the
// global-store queue (HIP's __syncthreads emits s_waitcnt vmcnt(0)).
__device__ __forceinline__ void block_sync_lds() {
    asm volatile("s_waitcnt lgkmcnt(0)" ::: "memory");
    __builtin_amdgcn_s_barrier();
    asm volatile("" ::: "memory");
}

// Force a wave-uniform float into an SGPR.
__device__ __forceinline__ float sgpr(float x) {
    return __int_as_float(__builtin_amdgcn_readfirstlane(__float_as_int(x)));
}

// HBM -> LDS direct staging, 16B per lane. LDS dest is wave-uniform base +
// lane*16; our per-lane pointers are exactly base+lane*16 (linear layout).
__device__ __forceinline__ void gload_lds16(const float* g, float* l) {
    __builtin_amdgcn_global_load_lds(
        (const __attribute__((address_space(1))) void*)g,
        (__attribute__((address_space(3))) void*)l, 16, 0, 0);
}

// ---------------------------------------------------------------------------
// 3x3 QR (LAPACK Householder convention). M = Phi_P[level] row-major;
// P out = Phi[level] row-major (orthonormal rows).
// ---------------------------------------------------------------------------
__device__ __forceinline__ void qr3(const float* __restrict__ M, float* __restrict__ P) {
    float A[3][3];
#pragma unroll
    for (int r = 0; r < 3; ++r)
#pragma unroll
        for (int c = 0; c < 3; ++c)
            A[r][c] = M[c * 3 + r];  // A = Phi_P^T

    float V[3][3], tau[3];
#pragma unroll
    for (int k = 0; k < 3; ++k) {
        float alpha = A[k][k];
        float xn2 = 0.f;
#pragma unroll
        for (int r = k + 1; r < 3; ++r) xn2 += A[r][k] * A[r][k];
        float t = 0.f;
        float v[3] = {0.f, 0.f, 0.f};
        v[k] = 1.f;
        if (xn2 > 0.f) {
            float beta = -copysignf(sqrtf(alpha * alpha + xn2), alpha);
            t = (beta - alpha) / beta;
            float inv = 1.f / (alpha - beta);
#pragma unroll
            for (int r = k + 1; r < 3; ++r) v[r] = A[r][k] * inv;
#pragma unroll
            for (int c = 0; c < 3; ++c) {
                if (c < k) continue;
                float w = 0.f;
#pragma unroll
                for (int r = 0; r < 3; ++r) if (r >= k) w += v[r] * A[r][c];
                w *= t;
#pragma unroll
                for (int r = 0; r < 3; ++r) if (r >= k) A[r][c] -= w * v[r];
            }
        }
        tau[k] = t;
#pragma unroll
        for (int r = 0; r < 3; ++r) V[k][r] = v[r];
    }
    float Q[3][3] = {{1.f, 0.f, 0.f}, {0.f, 1.f, 0.f}, {0.f, 0.f, 1.f}};
#pragma unroll
    for (int k = 2; k >= 0; --k) {
#pragma unroll
        for (int c = 0; c < 3; ++c) {
            float w = 0.f;
#pragma unroll
            for (int r = 0; r < 3; ++r) w += V[k][r] * Q[r][c];
            w *= tau[k];
#pragma unroll
            for (int r = 0; r < 3; ++r) Q[r][c] -= w * V[k][r];
        }
    }
#pragma unroll
    for (int r = 0; r < 3; ++r)
#pragma unroll
        for (int c = 0; c < 3; ++c)
            P[r * 3 + c] = Q[c][r];  // Phi = Q^T
}

// LDS staging origins (each section padded +8 for the alignment shift)
#define ORG_D1L0 0
#define ORG_D2L0 2312
#define ORG_D1L1 4624
#define ORG_D2L1 5400
#define ORG_D1L2 6176
#define ORG_D2L2 6440

// ---------------------------------------------------------------------------
// Fused 3 levels. Block = 256 L2-triples = 2304 L0 triples = 6912 input
// floats. Input staged HBM->LDS via global_load_lds (no VGPR round-trip),
// thread t then owns input floats [27t,27t+27). Details staged in LDS
// (shifted by A&3 so Phase-D reads are 16B-aligned), stored as NONTEMPORAL
// f32x4 (nt keeps out from evicting f's L3 residency; R5 lesson). Store
// queue never drained in-kernel after the initial staging barrier.
// ---------------------------------------------------------------------------
__global__ __launch_bounds__(TPB) void fused3_kernel(
        const float* __restrict__ in, float* __restrict__ out,
        float* __restrict__ avg_out, const float* __restrict__ PhiP,
        int lvl, int m2) {
    __shared__ float s[6912];
    const int  t = threadIdx.x;
    const long b = blockIdx.x;
    const long nF = 27L * m2;
    const long fBase = 6912L * b;
    const long M0 = 9L * m2, M1 = 3L * m2, M2 = m2;

    const bool full = (256L * (b + 1) <= (long)m2);  // all 256 L2-triples valid

    // global element offsets of this block's 6 detail chunks
    const long A0 = M0 + 2304L * b;
    const long A1 = 2 * M0 + 2304L * b;
    const long A2 = M1 + 768L * b;
    const long A3 = 2 * M1 + 768L * b;
    const long A4 = M2 + 256L * b;
    const long A5 = 2 * M2 + 256L * b;
    const int o0 = (int)(A0 & 3), o1 = (int)(A1 & 3), o2 = (int)(A2 & 3);
    const int o3 = (int)(A3 & 3), o4 = (int)(A4 & 3), o5 = (int)(A5 & 3);

    // ---- Phase A: direct HBM->LDS staging (7 wave-level rounds, all queued)
    if (full) {
        const float* src = in + fBase;
#pragma unroll
        for (int r = 0; r < 6; ++r) {
            int c = 256 * r + t;
            gload_lds16(src + 4 * c, &s[4 * c]);
        }
        if (t < 192) {  // wave-uniform (t in [192,256) is wave 3)
            int c = 1536 + t;
            gload_lds16(src + 4 * c, &s[4 * c]);
        }
    } else {
        const long rem = nF - fBase;
        for (int i = t; i < 6912; i += TPB) s[i] = (i < rem) ? in[fBase + i] : 0.f;
    }

    // ---- QR for the 3 levels (overlaps staging latency)
    float P[27];
    qr3(PhiP + 9L * lvl,       P + 0);
    qr3(PhiP + 9L * (lvl + 1), P + 9);
    qr3(PhiP + 9L * (lvl + 2), P + 18);
#pragma unroll
    for (int j = 0; j < 27; ++j) P[j] = sgpr(P[j]);

    __syncthreads();  // drains the global_load_lds queue (vmcnt) + barrier

    // ---- Phase B: transpose read, 27 consecutive floats per thread
    float f[27];
#pragma unroll
    for (int j = 0; j < 27; ++j) f[j] = s[27 * t + j];
    block_sync_lds();  // all reads done before s is overwritten

    // ---- Phase C: compute 3 levels in registers, stage details (shifted)
    float a[9];
#pragma unroll
    for (int g = 0; g < 9; ++g) {
        float x = f[3 * g], y = f[3 * g + 1], z = f[3 * g + 2];
        a[g] = x * P[0] + y * P[1] + z * P[2];
        s[ORG_D1L0 + o0 + 9 * t + g] = x * P[3] + y * P[4] + z * P[5];
        s[ORG_D2L0 + o1 + 9 * t + g] = x * P[6] + y * P[7] + z * P[8];
    }
    float bb[3];
#pragma unroll
    for (int h = 0; h < 3; ++h) {
        float x = a[3 * h], y = a[3 * h + 1], z = a[3 * h + 2];
        bb[h] = x * P[9] + y * P[10] + z * P[11];
        s[ORG_D1L1 + o2 + 3 * t + h] = x * P[12] + y * P[13] + z * P[14];
        s[ORG_D2L1 + o3 + 3 * t + h] = x * P[15] + y * P[16] + z * P[17];
    }
    float c;
    {
        float x = bb[0], y = bb[1], z = bb[2];
        c = x * P[18] + y * P[19] + z * P[20];
        s[ORG_D1L2 + o4 + t] = x * P[21] + y * P[22] + z * P[23];
        s[ORG_D2L2 + o5 + t] = x * P[24] + y * P[25] + z * P[26];
    }
    block_sync_lds();

    // ---- Phase D: nontemporal f32x4 store rounds (queue, never wait)
#define STORE_SEC(ORG, A, O, CNT, ROUNDS)                                      \
    {                                                                          \
        float* dst = out + (A);                                                \
        const int aH = (4 - (O)) & 3;                                          \
        const int nb = ((CNT) - aH) >> 2;                                      \
        const int tl = (CNT) - aH - 4 * nb;                                    \
        if (t < aH) __builtin_nontemporal_store(s[(ORG) + (O) + t], dst + t);  \
        _Pragma("unroll")                                                      \
        for (int r = 0; r < (ROUNDS); ++r) {                                   \
            int idx = 256 * r + t;                                             \
            if (idx < nb) {                                                    \
                f32x4 vv = *reinterpret_cast<const f32x4*>(                    \
                    &s[(ORG) + (O) + aH + 4 * idx]);                           \
                __builtin_nontemporal_store(                                   \
                    vv, reinterpret_cast<f32x4*>(dst + aH) + idx);             \
            }                                                                  \
        }                                                                      \
        if (t < tl)                                                            \
            __builtin_nontemporal_store(s[(ORG) + (O) + aH + 4 * nb + t],      \
                                        dst + aH + 4 * nb + t);                \
    }

    if (full) {
        STORE_SEC(ORG_D1L0, A0, o0, 2304, 3);
        STORE_SEC(ORG_D2L0, A1, o1, 2304, 3);
        STORE_SEC(ORG_D1L1, A2, o2, 768, 1);
        STORE_SEC(ORG_D2L1, A3, o3, 768, 1);
        STORE_SEC(ORG_D1L2, A4, o4, 256, 1);
        STORE_SEC(ORG_D2L2, A5, o5, 256, 1);
        avg_out[256L * b + t] = c;
    } else {
        // boundary block: bounds-checked dword stores from the shifted staging
#pragma unroll
        for (int r = 0; r < 9; ++r) {
            long i = 256 * r + t, g = 2304L * b + i;
            if (g < M0) {
                __builtin_nontemporal_store(s[ORG_D1L0 + o0 + i], out + M0 + g);
                __builtin_nontemporal_store(s[ORG_D2L0 + o1 + i], out + 2 * M0 + g);
            }
        }
#pragma unroll
        for (int r = 0; r < 3; ++r) {
            long i = 256 * r + t, g = 768L * b + i;
            if (g < M1) {
                __builtin_nontemporal_store(s[ORG_D1L1 + o2 + i], out + M1 + g);
                __builtin_nontemporal_store(s[ORG_D2L1 + o3 + i], out + 2 * M1 + g);
            }
        }
        long g = 256L * b + t;
        if (g < M2) {
            __builtin_nontemporal_store(s[ORG_D1L2 + o4 + t], out + M2 + g);
            __builtin_nontemporal_store(s[ORG_D2L2 + o5 + t], out + 2 * M2 + g);
            avg_out[g] = c;
        }
    }
#undef STORE_SEC
}

// ---------------------------------------------------------------------------
// Tail: levels 6..15 in ONE block of 1024 threads (replaces the old 9-block
// K3 + levels-9..15 tail). Input bufB = 3^10 floats (L2-resident, written by
// K2). Level 6 streams global->out/LDS; levels 7..15 ping-pong in LDS.
// Static LDS = 105 KB (gfx950 supports >64 KB/WG; cf. m201's 128 KB kernel).
// ---------------------------------------------------------------------------
#define TTPB 1024
__global__ __launch_bounds__(TTPB) void tail_kernel(
        const float* __restrict__ in, float* __restrict__ out,
        const float* __restrict__ PhiP) {
    __shared__ float s0[19683];
    __shared__ float s1[6561];
    __shared__ float sPhi[90];
    const int lt = threadIdx.x;

    if (lt < 10) {  // QR for levels 6..15, one per lane
        float P[9];
        qr3(PhiP + 9L * (6 + lt), P);
#pragma unroll
        for (int j = 0; j < 9; ++j) sPhi[lt * 9 + j] = P[j];
    }
    __syncthreads();

    // ---- level 6: global stride-3 reads (236 KB, L2-resident), m = 19683
    {
        float p0 = sPhi[0], p1 = sPhi[1], p2 = sPhi[2];
        float q0 = sPhi[3], q1 = sPhi[4], q2 = sPhi[5];
        float r0 = sPhi[6], r1 = sPhi[7], r2 = sPhi[8];
        for (int u = lt; u < 19683; u += TTPB) {
            float x = in[3 * u], y = in[3 * u + 1], z = in[3 * u + 2];
            out[19683 + u]     = x * q0 + y * q1 + z * q2;
            out[2 * 19683 + u] = x * r0 + y * r1 + z * r2;
            s0[u]              = x * p0 + y * p1 + z * p2;
        }
    }
    block_sync_lds();

    // ---- levels 7..15: LDS ping-pong
    float* cur = s0;
    float* nxt = s1;
    int len = 19683;
#pragma unroll
    for (int k = 1; k < 10; ++k) {
        int m = len / 3;
        float p0 = sPhi[k * 9 + 0], p1 = sPhi[k * 9 + 1], p2 = sPhi[k * 9 + 2];
        float q0 = sPhi[k * 9 + 3], q1 = sPhi[k * 9 + 4], q2 = sPhi[k * 9 + 5];
        float r0 = sPhi[k * 9 + 6], r1 = sPhi[k * 9 + 7], r2 = sPhi[k * 9 + 8];
        for (int u = lt; u < m; u += TTPB) {
            float x = cur[3 * u], y = cur[3 * u + 1], z = cur[3 * u + 2];
            out[m + u]     = x * q0 + y * q1 + z * q2;
            out[2 * m + u] = x * r0 + y * r1 + z * r2;
            nxt[u]         = x * p0 + y * p1 + z * p2;
        }
        block_sync_lds();
        float* tmp = cur; cur = nxt; nxt = tmp;
        len = m;
    }
    if (lt == 0) out[0] = cur[0];
}

extern "C" void kernel_launch(void* const* d_in, const int* in_sizes, int n_in,
                              void* d_out, int out_size, void* d_ws, size_t ws_size,
                              hipStream_t stream) {
    const float* f    = (const float*)d_in[0];   // 3^16 floats
    const float* PhiP = (const float*)d_in[1];   // 16*3*3 floats
    float* out = (float*)d_out;                  // 3^16 floats
    float* ws  = (float*)d_ws;

    float* bufA = ws;                // 3^13 floats (avg after levels 0-2)
    float* bufB = bufA + 1594323;    // 3^10 floats (avg after levels 3-5)

    const int m2_0 = 1594323;  // 3^13, levels 0-2
    fused3_kernel<<<(m2_0 + TPB - 1) / TPB, TPB, 0, stream>>>(f, out, bufA, PhiP, 0, m2_0);

    const int m2_1 = 59049;    // 3^10, levels 3-5
    fused3_kernel<<<(m2_1 + TPB - 1) / TPB, TPB, 0, stream>>>(bufA, out, bufB, PhiP, 3, m2_1);

    tail_kernel<<<1, TTPB, 0, stream>>>(bufB, out, PhiP);  // levels 6-15
}

// Round 9
// 72.388 us; speedup vs baseline: 1.9165x; 1.1577x over previous
//
#include <hip/hip_runtime.h>

#define TPB 256

typedef float f32x4 __attribute__((ext_vector_type(4)));

// lgkm-only barrier: orders LDS ops across the block without draining the
// global-store queue (HIP's __syncthreads emits s_waitcnt vmcnt(0)).
__device__ __forceinline__ void block_sync_lds() {
    asm volatile("s_waitcnt lgkmcnt(0)" ::: "memory");
    __builtin_amdgcn_s_barrier();
    asm volatile("" ::: "memory");
}

// Force a wave-uniform float into an SGPR.
__device__ __forceinline__ float sgpr(float x) {
    return __int_as_float(__builtin_amdgcn_readfirstlane(__float_as_int(x)));
}

// HBM -> LDS direct staging. LDS dest is wave-uniform base + lane*width;
// our layouts are linear so the constraint is satisfied.
__device__ __forceinline__ void gload_lds16(const float* g, float* l) {
    __builtin_amdgcn_global_load_lds(
        (const __attribute__((address_space(1))) void*)g,
        (__attribute__((address_space(3))) void*)l, 16, 0, 0);
}
__device__ __forceinline__ void gload_lds4(const float* g, float* l) {
    __builtin_amdgcn_global_load_lds(
        (const __attribute__((address_space(1))) void*)g,
        (__attribute__((address_space(3))) void*)l, 4, 0, 0);
}

// ---------------------------------------------------------------------------
// 3x3 QR (LAPACK Householder convention). M = Phi_P[level] row-major;
// P out = Phi[level] row-major (orthonormal rows).
// ---------------------------------------------------------------------------
__device__ __forceinline__ void qr3(const float* __restrict__ M, float* __restrict__ P) {
    float A[3][3];
#pragma unroll
    for (int r = 0; r < 3; ++r)
#pragma unroll
        for (int c = 0; c < 3; ++c)
            A[r][c] = M[c * 3 + r];  // A = Phi_P^T

    float V[3][3], tau[3];
#pragma unroll
    for (int k = 0; k < 3; ++k) {
        float alpha = A[k][k];
        float xn2 = 0.f;
#pragma unroll
        for (int r = k + 1; r < 3; ++r) xn2 += A[r][k] * A[r][k];
        float t = 0.f;
        float v[3] = {0.f, 0.f, 0.f};
        v[k] = 1.f;
        if (xn2 > 0.f) {
            float beta = -copysignf(sqrtf(alpha * alpha + xn2), alpha);
            t = (beta - alpha) / beta;
            float inv = 1.f / (alpha - beta);
#pragma unroll
            for (int r = k + 1; r < 3; ++r) v[r] = A[r][k] * inv;
#pragma unroll
            for (int c = 0; c < 3; ++c) {
                if (c < k) continue;
                float w = 0.f;
#pragma unroll
                for (int r = 0; r < 3; ++r) if (r >= k) w += v[r] * A[r][c];
                w *= t;
#pragma unroll
                for (int r = 0; r < 3; ++r) if (r >= k) A[r][c] -= w * v[r];
            }
        }
        tau[k] = t;
#pragma unroll
        for (int r = 0; r < 3; ++r) V[k][r] = v[r];
    }
    float Q[3][3] = {{1.f, 0.f, 0.f}, {0.f, 1.f, 0.f}, {0.f, 0.f, 1.f}};
#pragma unroll
    for (int k = 2; k >= 0; --k) {
#pragma unroll
        for (int c = 0; c < 3; ++c) {
            float w = 0.f;
#pragma unroll
            for (int r = 0; r < 3; ++r) w += V[k][r] * Q[r][c];
            w *= tau[k];
#pragma unroll
            for (int r = 0; r < 3; ++r) Q[r][c] -= w * V[k][r];
        }
    }
#pragma unroll
    for (int r = 0; r < 3; ++r)
#pragma unroll
        for (int c = 0; c < 3; ++c)
            P[r * 3 + c] = Q[c][r];  // Phi = Q^T
}

// LDS staging origins for K1 (each section padded +8 for the alignment shift)
#define ORG_D1L0 0
#define ORG_D2L0 2312
#define ORG_D1L1 4624
#define ORG_D2L1 5400
#define ORG_D1L2 6176
#define ORG_D2L2 6440

// ---------------------------------------------------------------------------
// K1: fused levels 0-2 (unchanged from R8 — proven at ~5.2 TB/s effective).
// ---------------------------------------------------------------------------
__global__ __launch_bounds__(TPB) void fused3_kernel(
        const float* __restrict__ in, float* __restrict__ out,
        float* __restrict__ avg_out, const float* __restrict__ PhiP,
        int lvl, int m2) {
    __shared__ float s[6912];
    const int  t = threadIdx.x;
    const long b = blockIdx.x;
    const long nF = 27L * m2;
    const long fBase = 6912L * b;
    const long M0 = 9L * m2, M1 = 3L * m2, M2 = m2;

    const bool full = (256L * (b + 1) <= (long)m2);

    const long A0 = M0 + 2304L * b;
    const long A1 = 2 * M0 + 2304L * b;
    const long A2 = M1 + 768L * b;
    const long A3 = 2 * M1 + 768L * b;
    const long A4 = M2 + 256L * b;
    const long A5 = 2 * M2 + 256L * b;
    const int o0 = (int)(A0 & 3), o1 = (int)(A1 & 3), o2 = (int)(A2 & 3);
    const int o3 = (int)(A3 & 3), o4 = (int)(A4 & 3), o5 = (int)(A5 & 3);

    // ---- Phase A: direct HBM->LDS staging
    if (full) {
        const float* src = in + fBase;
#pragma unroll
        for (int r = 0; r < 6; ++r) {
            int c = 256 * r + t;
            gload_lds16(src + 4 * c, &s[4 * c]);
        }
        if (t < 192) {
            int c = 1536 + t;
            gload_lds16(src + 4 * c, &s[4 * c]);
        }
    } else {
        const long rem = nF - fBase;
        for (int i = t; i < 6912; i += TPB) s[i] = (i < rem) ? in[fBase + i] : 0.f;
    }

    // ---- QR (overlaps staging latency)
    float P[27];
    qr3(PhiP + 9L * lvl,       P + 0);
    qr3(PhiP + 9L * (lvl + 1), P + 9);
    qr3(PhiP + 9L * (lvl + 2), P + 18);
#pragma unroll
    for (int j = 0; j < 27; ++j) P[j] = sgpr(P[j]);

    __syncthreads();  // drains the global_load_lds queue + barrier

    // ---- Phase B: transpose read
    float f[27];
#pragma unroll
    for (int j = 0; j < 27; ++j) f[j] = s[27 * t + j];
    block_sync_lds();

    // ---- Phase C: compute, stage details (shifted)
    float a[9];
#pragma unroll
    for (int g = 0; g < 9; ++g) {
        float x = f[3 * g], y = f[3 * g + 1], z = f[3 * g + 2];
        a[g] = x * P[0] + y * P[1] + z * P[2];
        s[ORG_D1L0 + o0 + 9 * t + g] = x * P[3] + y * P[4] + z * P[5];
        s[ORG_D2L0 + o1 + 9 * t + g] = x * P[6] + y * P[7] + z * P[8];
    }
    float bb[3];
#pragma unroll
    for (int h = 0; h < 3; ++h) {
        float x = a[3 * h], y = a[3 * h + 1], z = a[3 * h + 2];
        bb[h] = x * P[9] + y * P[10] + z * P[11];
        s[ORG_D1L1 + o2 + 3 * t + h] = x * P[12] + y * P[13] + z * P[14];
        s[ORG_D2L1 + o3 + 3 * t + h] = x * P[15] + y * P[16] + z * P[17];
    }
    float c;
    {
        float x = bb[0], y = bb[1], z = bb[2];
        c = x * P[18] + y * P[19] + z * P[20];
        s[ORG_D1L2 + o4 + t] = x * P[21] + y * P[22] + z * P[23];
        s[ORG_D2L2 + o5 + t] = x * P[24] + y * P[25] + z * P[26];
    }
    block_sync_lds();

    // ---- Phase D: nontemporal f32x4 store rounds
#define STORE_SEC(ORG, A, O, CNT, ROUNDS)                                      \
    {                                                                          \
        float* dst = out + (A);                                                \
        const int aH = (4 - (O)) & 3;                                          \
        const int nb = ((CNT) - aH) >> 2;                                      \
        const int tl = (CNT) - aH - 4 * nb;                                    \
        if (t < aH) __builtin_nontemporal_store(s[(ORG) + (O) + t], dst + t);  \
        _Pragma("unroll")                                                      \
        for (int r = 0; r < (ROUNDS); ++r) {                                   \
            int idx = 256 * r + t;                                             \
            if (idx < nb) {                                                    \
                f32x4 vv = *reinterpret_cast<const f32x4*>(                    \
                    &s[(ORG) + (O) + aH + 4 * idx]);                           \
                __builtin_nontemporal_store(                                   \
                    vv, reinterpret_cast<f32x4*>(dst + aH) + idx);             \
            }                                                                  \
        }                                                                      \
        if (t < tl)                                                            \
            __builtin_nontemporal_store(s[(ORG) + (O) + aH + 4 * nb + t],      \
                                        dst + aH + 4 * nb + t);                \
    }

    if (full) {
        STORE_SEC(ORG_D1L0, A0, o0, 2304, 3);
        STORE_SEC(ORG_D2L0, A1, o1, 2304, 3);
        STORE_SEC(ORG_D1L1, A2, o2, 768, 1);
        STORE_SEC(ORG_D2L1, A3, o3, 768, 1);
        STORE_SEC(ORG_D1L2, A4, o4, 256, 1);
        STORE_SEC(ORG_D2L2, A5, o5, 256, 1);
        avg_out[256L * b + t] = c;
    } else {
#pragma unroll
        for (int r = 0; r < 9; ++r) {
            long i = 256 * r + t, g = 2304L * b + i;
            if (g < M0) {
                __builtin_nontemporal_store(s[ORG_D1L0 + o0 + i], out + M0 + g);
                __builtin_nontemporal_store(s[ORG_D2L0 + o1 + i], out + 2 * M0 + g);
            }
        }
#pragma unroll
        for (int r = 0; r < 3; ++r) {
            long i = 256 * r + t, g = 768L * b + i;
            if (g < M1) {
                __builtin_nontemporal_store(s[ORG_D1L1 + o2 + i], out + M1 + g);
                __builtin_nontemporal_store(s[ORG_D2L1 + o3 + i], out + 2 * M1 + g);
            }
        }
        long g = 256L * b + t;
        if (g < M2) {
            __builtin_nontemporal_store(s[ORG_D1L2 + o4 + t], out + M2 + g);
            __builtin_nontemporal_store(s[ORG_D2L2 + o5 + t], out + 2 * M2 + g);
            avg_out[g] = c;
        }
    }
#undef STORE_SEC
}

// ---------------------------------------------------------------------------
// K2: fused levels 3-8. 243 blocks x 256 threads (243 active in compute).
// Block input = 6561 floats of bufA (3^8). Levels 3-5 thread-local (27
// floats/thread), levels 6-8 within-block via LDS on the 243 per-thread avgs.
// All details staged in LDS, then dense coalesced nt dword stores.
// Emits the level-8 avg (9/block, 2187 total) directly to bufC.
// Global detail bases: L3:3^12 L4:3^11 L5:3^10 L6:3^9 L7:3^8 L8:3^7.
// ---------------------------------------------------------------------------
__global__ __launch_bounds__(TPB) void mid_kernel(
        const float* __restrict__ in, float* __restrict__ out,
        float* __restrict__ avg_out, const float* __restrict__ PhiP) {
    // stage layout (floats):
    // D1L3 0..2187 | D2L3 2187..4374 | D1L4 4374..5103 | D2L4 5103..5832 |
    // D1L5 5832..6075 | D2L5 6075..6318 | D1L6 6318..6399 | D2L6 6399..6480 |
    // D1L7 6480..6507 | D2L7 6507..6534 | D1L8 6534..6543 | D2L8 6543..6552
    __shared__ float s[6912];
    __shared__ float sc[243];
    __shared__ float sc2[81];
    __shared__ float sc3[27];
    __shared__ float sPhi[54];
    const int  t = threadIdx.x;
    const long b = blockIdx.x;
    const float* src = in + 6561L * b;

    // ---- stage 6656 floats (reads up to 95 past block region: still in ws)
#pragma unroll
    for (int r = 0; r < 26; ++r) {
        int i = 256 * r + t;
        gload_lds4(src + i, &s[i]);
    }
    // QR for levels 3..8, one per lane (overlaps staging)
    if (t < 6) {
        float P[9];
        qr3(PhiP + 9L * (3 + t), P);
#pragma unroll
        for (int j = 0; j < 9; ++j) sPhi[9 * t + j] = P[j];
    }
    __syncthreads();  // drains gload_lds + sPhi visible

    float P[27];
#pragma unroll
    for (int j = 0; j < 27; ++j) P[j] = sgpr(sPhi[j]);

    float f27[27];
    const bool act = (t < 243);
    if (act) {
#pragma unroll
        for (int j = 0; j < 27; ++j) f27[j] = s[27 * t + j];
    }
    block_sync_lds();  // all input reads done before s is overwritten

    // ---- levels 3-5 thread-local
    if (act) {
        float a[9];
#pragma unroll
        for (int g = 0; g < 9; ++g) {
            float x = f27[3 * g], y = f27[3 * g + 1], z = f27[3 * g + 2];
            a[g] = x * P[0] + y * P[1] + z * P[2];
            s[9 * t + g]        = x * P[3] + y * P[4] + z * P[5];
            s[2187 + 9 * t + g] = x * P[6] + y * P[7] + z * P[8];
        }
        float bb[3];
#pragma unroll
        for (int h = 0; h < 3; ++h) {
            float x = a[3 * h], y = a[3 * h + 1], z = a[3 * h + 2];
            bb[h] = x * P[9] + y * P[10] + z * P[11];
            s[4374 + 3 * t + h] = x * P[12] + y * P[13] + z * P[14];
            s[5103 + 3 * t + h] = x * P[15] + y * P[16] + z * P[17];
        }
        float x = bb[0], y = bb[1], z = bb[2];
        sc[t]        = x * P[18] + y * P[19] + z * P[20];
        s[5832 + t]  = x * P[21] + y * P[22] + z * P[23];
        s[6075 + t]  = x * P[24] + y * P[25] + z * P[26];
    }
    block_sync_lds();

    // ---- level 6 (81 triples from sc)
    if (t < 81) {
        float x = sc[3 * t], y = sc[3 * t + 1], z = sc[3 * t + 2];
        sc2[t]      = x * sPhi[27] + y * sPhi[28] + z * sPhi[29];
        s[6318 + t] = x * sPhi[30] + y * sPhi[31] + z * sPhi[32];
        s[6399 + t] = x * sPhi[33] + y * sPhi[34] + z * sPhi[35];
    }
    block_sync_lds();
    // ---- level 7 (27 triples)
    if (t < 27) {
        float x = sc2[3 * t], y = sc2[3 * t + 1], z = sc2[3 * t + 2];
        sc3[t]      = x * sPhi[36] + y * sPhi[37] + z * sPhi[38];
        s[6480 + t] = x * sPhi[39] + y * sPhi[40] + z * sPhi[41];
        s[6507 + t] = x * sPhi[42] + y * sPhi[43] + z * sPhi[44];
    }
    block_sync_lds();
    // ---- level 8 (9 triples); avg goes straight to bufC
    if (t < 9) {
        float x = sc3[3 * t], y = sc3[3 * t + 1], z = sc3[3 * t + 2];
        avg_out[9 * b + t] = x * sPhi[45] + y * sPhi[46] + z * sPhi[47];
        s[6534 + t] = x * sPhi[48] + y * sPhi[49] + z * sPhi[50];
        s[6543 + t] = x * sPhi[51] + y * sPhi[52] + z * sPhi[53];
    }
    block_sync_lds();

    // ---- coalesced nt dword stores per section
    const long B0 = 2187L * b, B1 = 729L * b, B2 = 243L * b;
    const long B3 = 81L * b, B4 = 27L * b, B5 = 9L * b;
#pragma unroll
    for (int r = 0; r < 9; ++r) {
        int i = 256 * r + t;
        if (i < 2187) {
            __builtin_nontemporal_store(s[i],        out + 531441 + B0 + i);
            __builtin_nontemporal_store(s[2187 + i], out + 2 * 531441 + B0 + i);
        }
    }
#pragma unroll
    for (int r = 0; r < 3; ++r) {
        int i = 256 * r + t;
        if (i < 729) {
            __builtin_nontemporal_store(s[4374 + i], out + 177147 + B1 + i);
            __builtin_nontemporal_store(s[5103 + i], out + 2 * 177147 + B1 + i);
        }
    }
    if (t < 243) {
        __builtin_nontemporal_store(s[5832 + t], out + 59049 + B2 + t);
        __builtin_nontemporal_store(s[6075 + t], out + 2 * 59049 + B2 + t);
    }
    if (t < 81) {
        __builtin_nontemporal_store(s[6318 + t], out + 19683 + B3 + t);
        __builtin_nontemporal_store(s[6399 + t], out + 2 * 19683 + B3 + t);
    }
    if (t < 27) {
        __builtin_nontemporal_store(s[6480 + t], out + 6561 + B4 + t);
        __builtin_nontemporal_store(s[6507 + t], out + 2 * 6561 + B4 + t);
    }
    if (t < 9) {
        __builtin_nontemporal_store(s[6534 + t], out + 2187 + B5 + t);
        __builtin_nontemporal_store(s[6543 + t], out + 2 * 2187 + B5 + t);
    }
}

// ---------------------------------------------------------------------------
// Tail: levels 9..15, one block of 1024 threads, LDS ping-pong (input 2187).
// ---------------------------------------------------------------------------
#define TTPB 1024
__global__ __launch_bounds__(TTPB) void tail_kernel(
        const float* __restrict__ in, float* __restrict__ out,
        const float* __restrict__ PhiP) {
    __shared__ float s0[2187];
    __shared__ float s1[729];
    __shared__ float sPhi[63];
    const int lt = threadIdx.x;

    for (int i = lt; i < 2187; i += TTPB) s0[i] = in[i];
    if (lt < 7) {
        float P[9];
        qr3(PhiP + 9L * (9 + lt), P);
#pragma unroll
        for (int j = 0; j < 9; ++j) sPhi[lt * 9 + j] = P[j];
    }
    __syncthreads();

    float* cur = s0;
    float* nxt = s1;
    int len = 2187;
#pragma unroll
    for (int L = 0; L < 7; ++L) {
        int m = len / 3;
        float p0 = sPhi[L * 9 + 0], p1 = sPhi[L * 9 + 1], p2 = sPhi[L * 9 + 2];
        float q0 = sPhi[L * 9 + 3], q1 = sPhi[L * 9 + 4], q2 = sPhi[L * 9 + 5];
        float r0 = sPhi[L * 9 + 6], r1 = sPhi[L * 9 + 7], r2 = sPhi[L * 9 + 8];
        for (int t = lt; t < m; t += TTPB) {
            float x = cur[3 * t], y = cur[3 * t + 1], z = cur[3 * t + 2];
            out[m + t]     = x * q0 + y * q1 + z * q2;
            out[2 * m + t] = x * r0 + y * r1 + z * r2;
            nxt[t]         = x * p0 + y * p1 + z * p2;
        }
        block_sync_lds();
        float* tmp = cur; cur = nxt; nxt = tmp;
        len = m;
    }
    if (lt == 0) out[0] = cur[0];
}

extern "C" void kernel_launch(void* const* d_in, const int* in_sizes, int n_in,
                              void* d_out, int out_size, void* d_ws, size_t ws_size,
                              hipStream_t stream) {
    const float* f    = (const float*)d_in[0];   // 3^16 floats
    const float* PhiP = (const float*)d_in[1];   // 16*3*3 floats
    float* out = (float*)d_out;                  // 3^16 floats
    float* ws  = (float*)d_ws;

    float* bufA = ws;                // 3^13 floats (avg after levels 0-2)
    float* bufC = bufA + 1594323;    // 3^7 = 2187 floats (avg after levels 3-8)

    const int m2_0 = 1594323;  // 3^13, levels 0-2
    fused3_kernel<<<(m2_0 + TPB - 1) / TPB, TPB, 0, stream>>>(f, out, bufA, PhiP, 0, m2_0);

    mid_kernel<<<243, TPB, 0, stream>>>(bufA, out, bufC, PhiP);  // levels 3-8

    tail_kernel<<<1, TTPB, 0, stream>>>(bufC, out, PhiP);        // levels 9-15
}

// Round 10
// 69.599 us; speedup vs baseline: 1.9933x; 1.0401x over previous
//
#include <hip/hip_runtime.h>

#define TPB 256

typedef float f32x4 __attribute__((ext_vector_type(4)));

// lgkm-only barrier: orders LDS ops across the block without draining the
// global-store queue (HIP's __syncthreads emits s_waitcnt vmcnt(0)).
__device__ __forceinline__ void block_sync_lds() {
    asm volatile("s_waitcnt lgkmcnt(0)" ::: "memory");
    __builtin_amdgcn_s_barrier();
    asm volatile("" ::: "memory");
}

// Force a wave-uniform float into an SGPR.
__device__ __forceinline__ float sgpr(float x) {
    return __int_as_float(__builtin_amdgcn_readfirstlane(__float_as_int(x)));
}

// HBM -> LDS direct staging. LDS dest is wave-uniform base + lane*width;
// our layouts are linear so the constraint is satisfied.
__device__ __forceinline__ void gload_lds16(const float* g, float* l) {
    __builtin_amdgcn_global_load_lds(
        (const __attribute__((address_space(1))) void*)g,
        (__attribute__((address_space(3))) void*)l, 16, 0, 0);
}
__device__ __forceinline__ void gload_lds4(const float* g, float* l) {
    __builtin_amdgcn_global_load_lds(
        (const __attribute__((address_space(1))) void*)g,
        (__attribute__((address_space(3))) void*)l, 4, 0, 0);
}

// ---------------------------------------------------------------------------
// 3x3 QR (LAPACK Householder convention). M = Phi_P[level] row-major;
// P out = Phi[level] row-major (orthonormal rows).
// ---------------------------------------------------------------------------
__device__ __forceinline__ void qr3(const float* __restrict__ M, float* __restrict__ P) {
    float A[3][3];
#pragma unroll
    for (int r = 0; r < 3; ++r)
#pragma unroll
        for (int c = 0; c < 3; ++c)
            A[r][c] = M[c * 3 + r];  // A = Phi_P^T

    float V[3][3], tau[3];
#pragma unroll
    for (int k = 0; k < 3; ++k) {
        float alpha = A[k][k];
        float xn2 = 0.f;
#pragma unroll
        for (int r = k + 1; r < 3; ++r) xn2 += A[r][k] * A[r][k];
        float t = 0.f;
        float v[3] = {0.f, 0.f, 0.f};
        v[k] = 1.f;
        if (xn2 > 0.f) {
            float beta = -copysignf(sqrtf(alpha * alpha + xn2), alpha);
            t = (beta - alpha) / beta;
            float inv = 1.f / (alpha - beta);
#pragma unroll
            for (int r = k + 1; r < 3; ++r) v[r] = A[r][k] * inv;
#pragma unroll
            for (int c = 0; c < 3; ++c) {
                if (c < k) continue;
                float w = 0.f;
#pragma unroll
                for (int r = 0; r < 3; ++r) if (r >= k) w += v[r] * A[r][c];
                w *= t;
#pragma unroll
                for (int r = 0; r < 3; ++r) if (r >= k) A[r][c] -= w * v[r];
            }
        }
        tau[k] = t;
#pragma unroll
        for (int r = 0; r < 3; ++r) V[k][r] = v[r];
    }
    float Q[3][3] = {{1.f, 0.f, 0.f}, {0.f, 1.f, 0.f}, {0.f, 0.f, 1.f}};
#pragma unroll
    for (int k = 2; k >= 0; --k) {
#pragma unroll
        for (int c = 0; c < 3; ++c) {
            float w = 0.f;
#pragma unroll
            for (int r = 0; r < 3; ++r) w += V[k][r] * Q[r][c];
            w *= tau[k];
#pragma unroll
            for (int r = 0; r < 3; ++r) Q[r][c] -= w * V[k][r];
        }
    }
#pragma unroll
    for (int r = 0; r < 3; ++r)
#pragma unroll
        for (int c = 0; c < 3; ++c)
            P[r * 3 + c] = Q[c][r];  // Phi = Q^T
}

// K1 LDS staging origins (sections padded +8 for the alignment shift)
#define ORG_D1L0 0
#define ORG_D2L0 1160
#define ORG_D1L1 2320
#define ORG_D2L1 2712
#define ORG_D1L2 3104
#define ORG_D2L2 3240

// ---------------------------------------------------------------------------
// K1: fused levels 0-2. Block = 128 L2-triples = 1152 L0 triples = 3456
// input floats -> LDS 13.8 KB -> 8 blocks/CU (wave cap) = 32 waves/CU, 100%
// occupancy. I/O structure identical to the proven R8 kernel: gload_lds16
// staging, thread-local triples (t<128 own 27 consecutive floats), shifted
// LDS detail staging, nontemporal f32x4 stores (nt = load-bearing, R5
// lesson), lgkm-only barriers after the single staging drain.
// ---------------------------------------------------------------------------
__global__ __launch_bounds__(TPB, 8) void fused3_kernel(
        const float* __restrict__ in, float* __restrict__ out,
        float* __restrict__ avg_out, const float* __restrict__ PhiP,
        int lvl, int m2) {
    __shared__ float s[3456];
    const int  t = threadIdx.x;
    const long b = blockIdx.x;
    const long nF = 27L * m2;
    const long fBase = 3456L * b;
    const long M0 = 9L * m2, M1 = 3L * m2, M2 = m2;

    const bool full = (128L * (b + 1) <= (long)m2);

    const long A0 = M0 + 1152L * b;
    const long A1 = 2 * M0 + 1152L * b;
    const long A2 = M1 + 384L * b;
    const long A3 = 2 * M1 + 384L * b;
    const long A4 = M2 + 128L * b;
    const long A5 = 2 * M2 + 128L * b;
    const int o0 = (int)(A0 & 3), o1 = (int)(A1 & 3), o2 = (int)(A2 & 3);
    const int o3 = (int)(A3 & 3), o4 = (int)(A4 & 3), o5 = (int)(A5 & 3);

    // ---- Phase A: direct HBM->LDS staging (864 f32x4; round 3 re-covers the
    // tail 256 so every gload round runs with full exec — no partial waves)
    if (full) {
        const float* src = in + fBase;
#pragma unroll
        for (int r = 0; r < 3; ++r) {
            int c = 256 * r + t;
            gload_lds16(src + 4 * c, &s[4 * c]);
        }
        {
            int c = 608 + t;  // overlaps round 2 by 160 (same data, benign)
            gload_lds16(src + 4 * c, &s[4 * c]);
        }
    } else {
        const long rem = nF - fBase;
        for (int i = t; i < 3456; i += TPB) s[i] = (i < rem) ? in[fBase + i] : 0.f;
    }

    // ---- QR (overlaps staging latency)
    float P[27];
    qr3(PhiP + 9L * lvl,       P + 0);
    qr3(PhiP + 9L * (lvl + 1), P + 9);
    qr3(PhiP + 9L * (lvl + 2), P + 18);
#pragma unroll
    for (int j = 0; j < 27; ++j) P[j] = sgpr(P[j]);

    __syncthreads();  // drains the global_load_lds queue + barrier

    // ---- Phase B: transpose read (threads 0-127 own 27 consecutive floats)
    float f[27];
    const bool act = (t < 128);
    if (act) {
#pragma unroll
        for (int j = 0; j < 27; ++j) f[j] = s[27 * t + j];
    }
    block_sync_lds();  // all reads done before s is overwritten

    // ---- Phase C: compute, stage details (shifted)
    float c;
    if (act) {
        float a[9];
#pragma unroll
        for (int g = 0; g < 9; ++g) {
            float x = f[3 * g], y = f[3 * g + 1], z = f[3 * g + 2];
            a[g] = x * P[0] + y * P[1] + z * P[2];
            s[ORG_D1L0 + o0 + 9 * t + g] = x * P[3] + y * P[4] + z * P[5];
            s[ORG_D2L0 + o1 + 9 * t + g] = x * P[6] + y * P[7] + z * P[8];
        }
        float bb[3];
#pragma unroll
        for (int h = 0; h < 3; ++h) {
            float x = a[3 * h], y = a[3 * h + 1], z = a[3 * h + 2];
            bb[h] = x * P[9] + y * P[10] + z * P[11];
            s[ORG_D1L1 + o2 + 3 * t + h] = x * P[12] + y * P[13] + z * P[14];
            s[ORG_D2L1 + o3 + 3 * t + h] = x * P[15] + y * P[16] + z * P[17];
        }
        float x = bb[0], y = bb[1], z = bb[2];
        c = x * P[18] + y * P[19] + z * P[20];
        s[ORG_D1L2 + o4 + t] = x * P[21] + y * P[22] + z * P[23];
        s[ORG_D2L2 + o5 + t] = x * P[24] + y * P[25] + z * P[26];
    }
    block_sync_lds();

    // ---- Phase D: nontemporal f32x4 store rounds (queue, never wait)
#define STORE_SEC(ORG, A, O, CNT, ROUNDS)                                      \
    {                                                                          \
        float* dst = out + (A);                                                \
        const int aH = (4 - (O)) & 3;                                          \
        const int nb = ((CNT) - aH) >> 2;                                      \
        const int tl = (CNT) - aH - 4 * nb;                                    \
        if (t < aH) __builtin_nontemporal_store(s[(ORG) + (O) + t], dst + t);  \
        _Pragma("unroll")                                                      \
        for (int r = 0; r < (ROUNDS); ++r) {                                   \
            int idx = 256 * r + t;                                             \
            if (idx < nb) {                                                    \
                f32x4 vv = *reinterpret_cast<const f32x4*>(                    \
                    &s[(ORG) + (O) + aH + 4 * idx]);                           \
                __builtin_nontemporal_store(                                   \
                    vv, reinterpret_cast<f32x4*>(dst + aH) + idx);             \
            }                                                                  \
        }                                                                      \
        if (t < tl)                                                            \
            __builtin_nontemporal_store(s[(ORG) + (O) + aH + 4 * nb + t],      \
                                        dst + aH + 4 * nb + t);                \
    }

    if (full) {
        STORE_SEC(ORG_D1L0, A0, o0, 1152, 2);
        STORE_SEC(ORG_D2L0, A1, o1, 1152, 2);
        STORE_SEC(ORG_D1L1, A2, o2, 384, 1);
        STORE_SEC(ORG_D2L1, A3, o3, 384, 1);
        STORE_SEC(ORG_D1L2, A4, o4, 128, 1);
        STORE_SEC(ORG_D2L2, A5, o5, 128, 1);
        if (act) avg_out[128L * b + t] = c;
    } else {
        // boundary block: bounds-checked dword nt stores
#pragma unroll
        for (int r = 0; r < 5; ++r) {
            int i = 256 * r + t;
            long g = 1152L * b + i;
            if (i < 1152 && g < M0) {
                __builtin_nontemporal_store(s[ORG_D1L0 + o0 + i], out + M0 + g);
                __builtin_nontemporal_store(s[ORG_D2L0 + o1 + i], out + 2 * M0 + g);
            }
        }
#pragma unroll
        for (int r = 0; r < 2; ++r) {
            int i = 256 * r + t;
            long g = 384L * b + i;
            if (i < 384 && g < M1) {
                __builtin_nontemporal_store(s[ORG_D1L1 + o2 + i], out + M1 + g);
                __builtin_nontemporal_store(s[ORG_D2L1 + o3 + i], out + 2 * M1 + g);
            }
        }
        long g = 128L * b + t;
        if (act && g < M2) {
            __builtin_nontemporal_store(s[ORG_D1L2 + o4 + t], out + M2 + g);
            __builtin_nontemporal_store(s[ORG_D2L2 + o5 + t], out + 2 * M2 + g);
            avg_out[g] = c;
        }
    }
#undef STORE_SEC
}

// ---------------------------------------------------------------------------
// K2: fused levels 3-8 (unchanged from R9). 243 blocks x 256 threads.
// ---------------------------------------------------------------------------
__global__ __launch_bounds__(TPB) void mid_kernel(
        const float* __restrict__ in, float* __restrict__ out,
        float* __restrict__ avg_out, const float* __restrict__ PhiP) {
    __shared__ float s[6912];
    __shared__ float sc[243];
    __shared__ float sc2[81];
    __shared__ float sc3[27];
    __shared__ float sPhi[54];
    const int  t = threadIdx.x;
    const long b = blockIdx.x;
    const float* src = in + 6561L * b;

#pragma unroll
    for (int r = 0; r < 26; ++r) {
        int i = 256 * r + t;
        gload_lds4(src + i, &s[i]);
    }
    if (t < 6) {
        float P[9];
        qr3(PhiP + 9L * (3 + t), P);
#pragma unroll
        for (int j = 0; j < 9; ++j) sPhi[9 * t + j] = P[j];
    }
    __syncthreads();

    float P[27];
#pragma unroll
    for (int j = 0; j < 27; ++j) P[j] = sgpr(sPhi[j]);

    float f27[27];
    const bool act = (t < 243);
    if (act) {
#pragma unroll
        for (int j = 0; j < 27; ++j) f27[j] = s[27 * t + j];
    }
    block_sync_lds();

    if (act) {
        float a[9];
#pragma unroll
        for (int g = 0; g < 9; ++g) {
            float x = f27[3 * g], y = f27[3 * g + 1], z = f27[3 * g + 2];
            a[g] = x * P[0] + y * P[1] + z * P[2];
            s[9 * t + g]        = x * P[3] + y * P[4] + z * P[5];
            s[2187 + 9 * t + g] = x * P[6] + y * P[7] + z * P[8];
        }
        float bb[3];
#pragma unroll
        for (int h = 0; h < 3; ++h) {
            float x = a[3 * h], y = a[3 * h + 1], z = a[3 * h + 2];
            bb[h] = x * P[9] + y * P[10] + z * P[11];
            s[4374 + 3 * t + h] = x * P[12] + y * P[13] + z * P[14];
            s[5103 + 3 * t + h] = x * P[15] + y * P[16] + z * P[17];
        }
        float x = bb[0], y = bb[1], z = bb[2];
        sc[t]        = x * P[18] + y * P[19] + z * P[20];
        s[5832 + t]  = x * P[21] + y * P[22] + z * P[23];
        s[6075 + t]  = x * P[24] + y * P[25] + z * P[26];
    }
    block_sync_lds();

    if (t < 81) {
        float x = sc[3 * t], y = sc[3 * t + 1], z = sc[3 * t + 2];
        sc2[t]      = x * sPhi[27] + y * sPhi[28] + z * sPhi[29];
        s[6318 + t] = x * sPhi[30] + y * sPhi[31] + z * sPhi[32];
        s[6399 + t] = x * sPhi[33] + y * sPhi[34] + z * sPhi[35];
    }
    block_sync_lds();
    if (t < 27) {
        float x = sc2[3 * t], y = sc2[3 * t + 1], z = sc2[3 * t + 2];
        sc3[t]      = x * sPhi[36] + y * sPhi[37] + z * sPhi[38];
        s[6480 + t] = x * sPhi[39] + y * sPhi[40] + z * sPhi[41];
        s[6507 + t] = x * sPhi[42] + y * sPhi[43] + z * sPhi[44];
    }
    block_sync_lds();
    if (t < 9) {
        float x = sc3[3 * t], y = sc3[3 * t + 1], z = sc3[3 * t + 2];
        avg_out[9 * b + t] = x * sPhi[45] + y * sPhi[46] + z * sPhi[47];
        s[6534 + t] = x * sPhi[48] + y * sPhi[49] + z * sPhi[50];
        s[6543 + t] = x * sPhi[51] + y * sPhi[52] + z * sPhi[53];
    }
    block_sync_lds();

    const long B0 = 2187L * b, B1 = 729L * b, B2 = 243L * b;
    const long B3 = 81L * b, B4 = 27L * b, B5 = 9L * b;
#pragma unroll
    for (int r = 0; r < 9; ++r) {
        int i = 256 * r + t;
        if (i < 2187) {
            __builtin_nontemporal_store(s[i],        out + 531441 + B0 + i);
            __builtin_nontemporal_store(s[2187 + i], out + 2 * 531441 + B0 + i);
        }
    }
#pragma unroll
    for (int r = 0; r < 3; ++r) {
        int i = 256 * r + t;
        if (i < 729) {
            __builtin_nontemporal_store(s[4374 + i], out + 177147 + B1 + i);
            __builtin_nontemporal_store(s[5103 + i], out + 2 * 177147 + B1 + i);
        }
    }
    if (t < 243) {
        __builtin_nontemporal_store(s[5832 + t], out + 59049 + B2 + t);
        __builtin_nontemporal_store(s[6075 + t], out + 2 * 59049 + B2 + t);
    }
    if (t < 81) {
        __builtin_nontemporal_store(s[6318 + t], out + 19683 + B3 + t);
        __builtin_nontemporal_store(s[6399 + t], out + 2 * 19683 + B3 + t);
    }
    if (t < 27) {
        __builtin_nontemporal_store(s[6480 + t], out + 6561 + B4 + t);
        __builtin_nontemporal_store(s[6507 + t], out + 2 * 6561 + B4 + t);
    }
    if (t < 9) {
        __builtin_nontemporal_store(s[6534 + t], out + 2187 + B5 + t);
        __builtin_nontemporal_store(s[6543 + t], out + 2 * 2187 + B5 + t);
    }
}

// ---------------------------------------------------------------------------
// Tail: levels 9..15, one block of 1024 threads, LDS ping-pong (input 2187).
// ---------------------------------------------------------------------------
#define TTPB 1024
__global__ __launch_bounds__(TTPB) void tail_kernel(
        const float* __restrict__ in, float* __restrict__ out,
        const float* __restrict__ PhiP) {
    __shared__ float s0[2187];
    __shared__ float s1[729];
    __shared__ float sPhi[63];
    const int lt = threadIdx.x;

    for (int i = lt; i < 2187; i += TTPB) s0[i] = in[i];
    if (lt < 7) {
        float P[9];
        qr3(PhiP + 9L * (9 + lt), P);
#pragma unroll
        for (int j = 0; j < 9; ++j) sPhi[lt * 9 + j] = P[j];
    }
    __syncthreads();

    float* cur = s0;
    float* nxt = s1;
    int len = 2187;
#pragma unroll
    for (int L = 0; L < 7; ++L) {
        int m = len / 3;
        float p0 = sPhi[L * 9 + 0], p1 = sPhi[L * 9 + 1], p2 = sPhi[L * 9 + 2];
        float q0 = sPhi[L * 9 + 3], q1 = sPhi[L * 9 + 4], q2 = sPhi[L * 9 + 5];
        float r0 = sPhi[L * 9 + 6], r1 = sPhi[L * 9 + 7], r2 = sPhi[L * 9 + 8];
        for (int t = lt; t < m; t += TTPB) {
            float x = cur[3 * t], y = cur[3 * t + 1], z = cur[3 * t + 2];
            out[m + t]     = x * q0 + y * q1 + z * q2;
            out[2 * m + t] = x * r0 + y * r1 + z * r2;
            nxt[t]         = x * p0 + y * p1 + z * p2;
        }
        block_sync_lds();
        float* tmp = cur; cur = nxt; nxt = tmp;
        len = m;
    }
    if (lt == 0) out[0] = cur[0];
}

extern "C" void kernel_launch(void* const* d_in, const int* in_sizes, int n_in,
                              void* d_out, int out_size, void* d_ws, size_t ws_size,
                              hipStream_t stream) {
    const float* f    = (const float*)d_in[0];   // 3^16 floats
    const float* PhiP = (const float*)d_in[1];   // 16*3*3 floats
    float* out = (float*)d_out;                  // 3^16 floats
    float* ws  = (float*)d_ws;

    float* bufA = ws;                // 3^13 floats (avg after levels 0-2)
    float* bufC = bufA + 1594323;    // 3^7 = 2187 floats (avg after levels 3-8)

    const int m2_0 = 1594323;  // 3^13, levels 0-2
    const int grid1 = (m2_0 + 127) / 128;  // 12456 blocks
    fused3_kernel<<<grid1, TPB, 0, stream>>>(f, out, bufA, PhiP, 0, m2_0);

    mid_kernel<<<243, TPB, 0, stream>>>(bufA, out, bufC, PhiP);  // levels 3-8

    tail_kernel<<<1, TTPB, 0, stream>>>(bufC, out, PhiP);        // levels 9-15
}